// Round 10
// baseline (44.367 us; speedup 1.0000x reference)
//
#include <hip/hip_runtime.h>
#include <hip/hip_bf16.h>
#include <stdint.h>

typedef __attribute__((ext_vector_type(8))) short short8;
typedef __attribute__((ext_vector_type(4))) float f32x4;
typedef __attribute__((ext_vector_type(2))) float f32x2;
typedef __attribute__((ext_vector_type(4))) int i32x4;

#define RANGE  51200   // nodes per LDS half-range (u16 counters -> 100KB); %64==0
#define RWORDS 25600   // u32 words per range histogram
#define NSL    64      // edge slices; per-block edges = E/NSL (u16-safe if <=60000)
#define NFRAG  16      // frag-prep blocks (16384 threads total)

static __device__ __forceinline__ short to_bf16s(float f) {
  __hip_bfloat16 h = __float2bfloat16(f);
  return __builtin_bit_cast(short, h);
}

// ---------------------------------------------------------------------------
// Fused: blocks [0,NFRAG) convert W1 -> bf16 MFMA B-fragments; blocks
// [NFRAG, NFRAG+2*NSL) build per-(slice,range) u16 histograms of
// src = edge_index[0] in LDS. dst is algebraically unused (the final mean
// over all nodes collapses segment_sum to sum_e h[src[e]]).
// Ranges interleaved in the LSB (h&1) so the two blocks scanning the same
// edge slice co-schedule -> second read is an L2/L3 hit.
// u16 safety: each block sees <= E/NSL edges < 65535 -> no overflow, no
// spill, no global pre-zeroing, fire-and-forget LDS atomics.
// NOTE: no __threadfence anywhere — agent-scope fences on gfx950 emit
// L2 writeback+invalidate; 782 of them cost ~90us in R6/R7.
__global__ __launch_bounds__(1024) void k_histprep(
    const int* __restrict__ e, unsigned* __restrict__ priv,
    short* __restrict__ frag, const float* __restrict__ W1, int E) {
  __shared__ unsigned cnt[RWORDS];
  __shared__ int is64s;
  int b = blockIdx.x, tid = threadIdx.x;
  if (b < NFRAG) {
    int idx = b * 1024 + tid;  // k*128 + col
    int k = idx >> 7, col = idx & 127;
    int ct = col >> 4, ks = k >> 5, lh = (k >> 3) & 3, ee = k & 7;
    int lane = lh * 16 + (col & 15);
    frag[((ct * 4 + ks) * 64 + lane) * 8 + ee] = to_bf16s(W1[idx]);
    return;
  }
  int h = b - NFRAG;
  int r = h & 1, s = h >> 1;  // range interleaved; slice
  if (tid < 64) {  // layout detect: int64 -> high dwords all zero (LE)
    unsigned long long bl = __ballot(e[2 * tid + 1] == 0);
    if (tid == 0) is64s = (__popcll(bl) > 32) ? 1 : 0;
  }
  for (int j = tid; j < RWORDS; j += 1024) cnt[j] = 0u;
  __syncthreads();
  int is64 = is64s;
  unsigned base = (unsigned)r * RANGE;
  int nq = E >> 2;
  int qlo = (int)((long long)s * nq / NSL);
  int qhi = (int)((long long)(s + 1) * nq / NSL);
  for (int q = qlo + tid; q < qhi; q += 1024) {
    i32x4 v;
    if (is64) {
      i32x4 a = *reinterpret_cast<const i32x4*>(e + 8 * (size_t)q);
      i32x4 bb = *reinterpret_cast<const i32x4*>(e + 8 * (size_t)q + 4);
      v = i32x4{a[0], a[2], bb[0], bb[2]};
    } else {
      v = *reinterpret_cast<const i32x4*>(e + 4 * (size_t)q);
    }
#pragma unroll
    for (int k = 0; k < 4; ++k) {
      unsigned loc = (unsigned)v[k] - base;
      if (loc < (unsigned)RANGE)
        atomicAdd(&cnt[loc >> 1], 1u << (16 * (loc & 1)));
    }
  }
  if (s == 0) {  // tail edges (E%4), once per range
    int tail = E & 3;
    if (tid < tail) {
      int idx = E - tail + tid;
      unsigned loc = (unsigned)(is64 ? e[2 * idx] : e[idx]) - base;
      if (loc < (unsigned)RANGE)
        atomicAdd(&cnt[loc >> 1], 1u << (16 * (loc & 1)));
    }
  }
  __syncthreads();
  unsigned* dst = priv + (size_t)h * RWORDS;
  for (int j = tid; j < RWORDS; j += 1024) dst[j] = cnt[j];
}

// ---------------------------------------------------------------------------
// Merge NSL u16 copies per range -> wdeg = 1 + deg. Coalesced: consecutive
// threads read consecutive words; copies at stride 2*RWORDS (h = 2s+r).
__global__ __launch_bounds__(256) void k_merge(const unsigned* __restrict__ priv,
                                               float* __restrict__ wdeg, int N) {
  int g = blockIdx.x * 256 + threadIdx.x;
  if (g >= 2 * RWORDS) return;
  int r = (g >= RWORDS) ? 1 : 0;
  int word = g - r * RWORDS;
  const unsigned* p = priv + (size_t)r * RWORDS + word;
  unsigned lo = 0, hi = 0;
#pragma unroll 8
  for (int s = 0; s < NSL; ++s) {
    unsigned v = p[(size_t)(2 * s) * RWORDS];
    lo += v & 0xFFFFu;
    hi += v >> 16;
  }
  int n0 = r * RANGE + 2 * word;
  if (n0 + 1 < N) {
    *reinterpret_cast<f32x2*>(wdeg + n0) =
        f32x2{1.0f + (float)lo, 1.0f + (float)hi};
  } else if (n0 < N) {
    wdeg[n0] = 1.0f + (float)lo;
  }
}

// ---------------------------------------------------------------------------
// Main: s[j] = sum_n wdeg[n]*relu((X@W1)[n][j]+b1[j]), j=0..127.
// Waves fully independent: each owns 16-row chunks; A-fragments loaded
// DIRECTLY from global (8 contiguous floats at X[row*128+ks*32+kh*8] — a
// wave covers 16 rows x 128B contiguous per ks: coalesced). No A-staging,
// no per-chunk barriers. B-frags (W1) from LDS (conflict-free b128 reads).
__global__ __launch_bounds__(256) void k_main(
    const float* __restrict__ X, const short* __restrict__ w1frag,
    const float* __restrict__ b1, const float* __restrict__ wdeg,
    float* __restrict__ partials, int nNodes) {
  __shared__ __align__(16) short w1s[16384];  // 32KB W1 B-frags
  __shared__ float sred[128];

  int tid = threadIdx.x;
  {
    const f32x4* src = reinterpret_cast<const f32x4*>(w1frag);
    f32x4* dst = reinterpret_cast<f32x4*>(w1s);
#pragma unroll
    for (int i = 0; i < 8; ++i) dst[tid + i * 256] = src[tid + i * 256];
  }
  if (tid < 128) sred[tid] = 0.f;

  int lane = tid & 63, wave = tid >> 6;
  int rA = lane & 15;   // A-row in chunk / C-col low bits
  int kh = lane >> 4;   // k-offset group (0..3) / C-row group

  float b1r[8];
#pragma unroll
  for (int ct = 0; ct < 8; ++ct) b1r[ct] = b1[ct * 16 + rA];

  float sl[8] = {0, 0, 0, 0, 0, 0, 0, 0};
  int nChunks = (nNodes + 15) >> 4;
  int gw = blockIdx.x * 4 + wave;
  int nw = gridDim.x * 4;
  __syncthreads();

  for (int c = gw; c < nChunks; c += nw) {
    int row0 = c << 4;
    int rowA = row0 + rA;
    if (rowA > nNodes - 1) rowA = nNodes - 1;
    const float* xp = X + (size_t)rowA * 128 + kh * 8;

    f32x4 acc[8];
#pragma unroll
    for (int ct = 0; ct < 8; ++ct) acc[ct] = f32x4{0.f, 0.f, 0.f, 0.f};

#pragma unroll
    for (int ks = 0; ks < 4; ++ks) {
      f32x4 lo = *reinterpret_cast<const f32x4*>(xp + ks * 32);
      f32x4 hi = *reinterpret_cast<const f32x4*>(xp + ks * 32 + 4);
      short8 a;
#pragma unroll
      for (int ee = 0; ee < 4; ++ee) {
        a[ee] = to_bf16s(lo[ee]);
        a[4 + ee] = to_bf16s(hi[ee]);
      }
#pragma unroll
      for (int ct = 0; ct < 8; ++ct) {
        short8 bfr = *reinterpret_cast<const short8*>(
            &w1s[((ct * 4 + ks) * 64 + lane) * 8]);
        acc[ct] = __builtin_amdgcn_mfma_f32_16x16x32_bf16(a, bfr, acc[ct], 0, 0, 0);
      }
    }

    // epilogue: C elem (ct,rr): row = row0 + kh*4 + rr, col = ct*16 + rA
#pragma unroll
    for (int rr = 0; rr < 4; ++rr) {
      int row = row0 + kh * 4 + rr;
      float w = (row < nNodes) ? wdeg[row] : 0.0f;
#pragma unroll
      for (int ct = 0; ct < 8; ++ct)
        sl[ct] += w * fmaxf(acc[ct][rr] + b1r[ct], 0.f);
    }
  }

  // fold lane groups -> sred -> partials[blockIdx] (plain store)
#pragma unroll
  for (int ct = 0; ct < 8; ++ct) {
    float v = sl[ct];
    v += __shfl_xor(v, 16);
    v += __shfl_xor(v, 32);
    if (kh == 0) atomicAdd(&sred[ct * 16 + rA], v);
  }
  __syncthreads();
  if (tid < 128) partials[(size_t)blockIdx.x * 128 + tid] = sred[tid];
}

// ---------------------------------------------------------------------------
// Reduce partials[B][128] -> sv; out = ((sv@W2 + (N+E)*b2)/N)@Wp + bp.
// Single block, 1024 threads; 32-way sliced f32x4 reduction, unrolled MLP.
__global__ __launch_bounds__(1024) void k_final(
    const float* __restrict__ partials, int B, const float* __restrict__ W2,
    const float* __restrict__ b2, const float* __restrict__ Wp,
    const float* __restrict__ bp, float* __restrict__ out,
    float totalW, float invN) {
  __shared__ float accsA[32 * 128];  // 16KB
  __shared__ float sv[128];
  __shared__ float pooled[128];
  int t = threadIdx.x;
  {  // phase A: 32 slices x 32 f32x4 col-groups over B rows
    int cg = t & 31, slc = t >> 5;
    f32x4 s = f32x4{0.f, 0.f, 0.f, 0.f};
    for (int r = slc; r < B; r += 32)
      s += *reinterpret_cast<const f32x4*>(partials + (size_t)r * 128 + cg * 4);
    *reinterpret_cast<f32x4*>(&accsA[slc * 128 + cg * 4]) = s;
  }
  __syncthreads();
  if (t < 128) {
    float v = 0.f;
#pragma unroll
    for (int i = 0; i < 32; ++i) v += accsA[i * 128 + t];
    sv[t] = v;
  }
  __syncthreads();
  {  // pooled = (sv@W2 + totalW*b2)*invN ; 8 k-slices x 128 cols
    int col = t & 127, sl8 = t >> 7;
    float a = 0.f;
#pragma unroll
    for (int kk = 0; kk < 16; ++kk) {
      int k = sl8 * 16 + kk;
      a += sv[k] * W2[k * 128 + col];
    }
    accsA[sl8 * 128 + col] = a;
  }
  __syncthreads();
  if (t < 128) {
    float v = totalW * b2[t];
#pragma unroll
    for (int i = 0; i < 8; ++i) v += accsA[i * 128 + t];
    pooled[t] = v * invN;
  }
  __syncthreads();
  if (t < 512) {  // out = pooled@Wp + bp ; 64 outs x 8 k-slices
    int o = t & 63, s2 = t >> 6;
    float a = 0.f;
#pragma unroll
    for (int kk = 0; kk < 16; ++kk) {
      int k = s2 * 16 + kk;
      a += pooled[k] * Wp[k * 64 + o];
    }
    accsA[s2 * 64 + o] = a;
  }
  __syncthreads();
  if (t < 64) {
    float v = bp[t];
#pragma unroll
    for (int i = 0; i < 8; ++i) v += accsA[i * 64 + t];
    out[t] = v;
  }
}

// ---------------------------------------------------------------------------
// Fallback path (ws too small / shapes out of range): zero + atomic hist + cvt.
__global__ void k_zero(unsigned* __restrict__ p, int n) {
  int i = blockIdx.x * 256 + threadIdx.x;
  if (i < n) p[i] = 0u;
}
__global__ __launch_bounds__(256) void k_hist_fb(const int* __restrict__ e,
                                                 unsigned* __restrict__ deg,
                                                 int E) {
  __shared__ int is64s;
  int tid = threadIdx.x;
  if (tid < 64) {
    unsigned long long bl = __ballot(e[2 * tid + 1] == 0);
    if (tid == 0) is64s = (__popcll(bl) > 32) ? 1 : 0;
  }
  __syncthreads();
  int is64 = is64s;
  int stride = gridDim.x * blockDim.x;
  for (int i = blockIdx.x * blockDim.x + tid; i < E; i += stride)
    atomicAdd(&deg[is64 ? (unsigned)e[2 * i] : (unsigned)e[i]], 1u);
}
__global__ void k_cvt(const unsigned* __restrict__ deg,
                      float* __restrict__ wdeg, int N) {
  int i = blockIdx.x * 256 + threadIdx.x;
  if (i < N) wdeg[i] = 1.0f + (float)deg[i];
}

// ---------------------------------------------------------------------------
extern "C" void kernel_launch(void* const* d_in, const int* in_sizes, int n_in,
                              void* d_out, int out_size, void* d_ws, size_t ws_size,
                              hipStream_t stream) {
  const float* X  = (const float*)d_in[0];
  const int*   ei = (const int*)d_in[1];
  const float* W1 = (const float*)d_in[2];
  const float* b1 = (const float*)d_in[3];
  const float* W2 = (const float*)d_in[4];
  const float* b2 = (const float*)d_in[5];
  const float* Wp = (const float*)d_in[6];
  const float* bp = (const float*)d_in[7];

  int N = in_sizes[0] / 128;
  int E = in_sizes[1] / 2;
  int nChunks = (N + 15) >> 4;  // 16-row wave-chunks (6250 at N=100K)
  // grid: 782 blocks -> 3128 waves x 2 chunks = 6256 (99.9% balance)
  int mb = 782;
  if (nChunks < 2 * mb) mb = (nChunks + 7) / 8 * 2;  // small-N: shrink
  if (mb < 1) mb = 1;

  size_t privB = (size_t)2 * NSL * RWORDS * 4;                // 13.1 MB
  size_t fragB = (16384 * 2 + 255) & ~(size_t)255;
  size_t wdegB = ((size_t)N * 4 + 255) & ~(size_t)255;
  size_t partB = ((size_t)mb * 128 * 4 + 255) & ~(size_t)255;
  size_t fixed = privB + fragB + wdegB + partB + 512;

  bool fast = (N <= 2 * RANGE) && (E / NSL <= 60000) && (ws_size >= fixed);

  char* p = (char*)d_ws;
  unsigned* priv = (unsigned*)p;  p += privB;
  short* frag = (short*)p;        p += fragB;
  float* wdeg = (float*)p;        p += wdegB;
  float* parts = (float*)p;

  if (fast) {
    k_histprep<<<NFRAG + 2 * NSL, 1024, 0, stream>>>(ei, priv, frag, W1, E);
    k_merge<<<(2 * RWORDS + 255) / 256, 256, 0, stream>>>(priv, wdeg, N);
  } else {
    k_histprep<<<NFRAG, 1024, 0, stream>>>(ei, priv, frag, W1, E);
    k_zero<<<(N + 255) / 256, 256, 0, stream>>>((unsigned*)wdeg, N);
    k_hist_fb<<<2048, 256, 0, stream>>>(ei, (unsigned*)wdeg, E);
    k_cvt<<<(N + 255) / 256, 256, 0, stream>>>((unsigned*)wdeg, wdeg, N);
  }
  k_main<<<mb, 256, 0, stream>>>(X, frag, b1, wdeg, parts, N);
  k_final<<<1, 1024, 0, stream>>>(parts, mb, W2, b2, Wp, bp, (float*)d_out,
                                  (float)N + (float)E, 1.0f / (float)N);
}

// Round 11
// 37.024 us; speedup vs baseline: 1.1983x; 1.1983x over previous
//
#include <hip/hip_runtime.h>
#include <hip/hip_bf16.h>
#include <stdint.h>

typedef __attribute__((ext_vector_type(8))) short short8;
typedef __attribute__((ext_vector_type(4))) float f32x4;
typedef __attribute__((ext_vector_type(2))) float f32x2;
typedef __attribute__((ext_vector_type(4))) int i32x4;

#define NRANGE 4       // node ranges
#define RNODES 25600   // nodes per range (u16 counters -> 50KB LDS); %64==0
#define RW     12800   // u32 words per range histogram
#define NS     32      // edge slices; per-block edges = E/NS (u16-safe <= 65000)
#define NFRAG  16      // frag-prep blocks (16384 threads total)

static __device__ __forceinline__ short to_bf16s(float f) {
  __hip_bfloat16 h = __float2bfloat16(f);
  return __builtin_bit_cast(short, h);
}

// ---------------------------------------------------------------------------
// Fused: blocks [0,NFRAG) convert W1 -> bf16 MFMA B-fragments; blocks
// [NFRAG, NFRAG+NRANGE*NS) build per-(range,slice) u16 histograms of
// src = edge_index[0] in LDS. dst is algebraically unused (the final mean
// over all nodes collapses segment_sum to sum_e h[src[e]]).
// u16 safety: per-block edges = E/NS < 65535 -> no overflow, no spill, no
// global pre-zeroing, fire-and-forget LDS atomics. Edge re-reads across the
// NRANGE passes hit L3 (8MB << 256MB). No __threadfence anywhere (R6/R7
// lesson: agent-scope fences = L2 wb+inv, ~90us at 782 blocks).
__global__ __launch_bounds__(1024) void k_histprep(
    const int* __restrict__ e, unsigned* __restrict__ priv,
    short* __restrict__ frag, const float* __restrict__ W1, int E) {
  __shared__ unsigned cnt[RW];
  __shared__ int is64s;
  int b = blockIdx.x, tid = threadIdx.x;
  if (b < NFRAG) {
    int idx = b * 1024 + tid;  // k*128 + col
    int k = idx >> 7, col = idx & 127;
    int ct = col >> 4, ks = k >> 5, lh = (k >> 3) & 3, ee = k & 7;
    int lane = lh * 16 + (col & 15);
    frag[((ct * 4 + ks) * 64 + lane) * 8 + ee] = to_bf16s(W1[idx]);
    return;
  }
  int h = b - NFRAG;
  int r = h / NS, s = h % NS;  // range, edge-slice
  if (tid < 64) {  // layout detect: int64 -> high dwords all zero (LE)
    unsigned long long bl = __ballot(e[2 * tid + 1] == 0);
    if (tid == 0) is64s = (__popcll(bl) > 32) ? 1 : 0;
  }
  for (int j = tid; j < RW; j += 1024) cnt[j] = 0u;
  __syncthreads();
  int is64 = is64s;
  unsigned base = (unsigned)r * RNODES;
  int nq = E >> 2;
  int qlo = (int)((long long)s * nq / NS);
  int qhi = (int)((long long)(s + 1) * nq / NS);
  for (int q = qlo + tid; q < qhi; q += 1024) {
    i32x4 v;
    if (is64) {
      i32x4 a = *reinterpret_cast<const i32x4*>(e + 8 * (size_t)q);
      i32x4 bb = *reinterpret_cast<const i32x4*>(e + 8 * (size_t)q + 4);
      v = i32x4{a[0], a[2], bb[0], bb[2]};
    } else {
      v = *reinterpret_cast<const i32x4*>(e + 4 * (size_t)q);
    }
#pragma unroll
    for (int k = 0; k < 4; ++k) {
      unsigned loc = (unsigned)v[k] - base;
      if (loc < (unsigned)RNODES)
        atomicAdd(&cnt[loc >> 1], 1u << (16 * (loc & 1)));
    }
  }
  if (s == 0) {  // tail edges (E%4), once per range
    int tail = E & 3;
    if (tid < tail) {
      int idx = E - tail + tid;
      unsigned loc = (unsigned)(is64 ? e[2 * idx] : e[idx]) - base;
      if (loc < (unsigned)RNODES)
        atomicAdd(&cnt[loc >> 1], 1u << (16 * (loc & 1)));
    }
  }
  __syncthreads();
  unsigned* dst = priv + (size_t)h * RW;
  for (int j = tid; j < RW; j += 1024) dst[j] = cnt[j];
}

// ---------------------------------------------------------------------------
// Merge NS u16 copies per range -> wdeg = 1 + deg. Coalesced: consecutive
// threads read consecutive words within each copy.
__global__ __launch_bounds__(256) void k_merge(const unsigned* __restrict__ priv,
                                               float* __restrict__ wdeg, int N) {
  int g = blockIdx.x * 256 + threadIdx.x;
  if (g >= NRANGE * RW) return;
  int r = g / RW, word = g % RW;
  const unsigned* p = priv + (size_t)(r * NS) * RW + word;
  unsigned lo = 0, hi = 0;
#pragma unroll 8
  for (int s = 0; s < NS; ++s) {
    unsigned v = p[(size_t)s * RW];
    lo += v & 0xFFFFu;
    hi += v >> 16;
  }
  int n0 = r * RNODES + 2 * word;
  if (n0 + 1 < N) {
    *reinterpret_cast<f32x2*>(wdeg + n0) =
        f32x2{1.0f + (float)lo, 1.0f + (float)hi};
  } else if (n0 < N) {
    wdeg[n0] = 1.0f + (float)lo;
  }
}

// ---------------------------------------------------------------------------
// Main: s[j] = sum_n wdeg[n]*relu((X@W1)[n][j]+b1[j]), j=0..127.
// 64-row chunks: block-cooperative COALESCED X load (512B/row stripes ->
// measured faster than direct 128B-segment fragment loads, R10 post-mortem),
// bf16-convert, XOR-swizzled LDS tile; MFMA from ds_read_b128; 2 barriers
// per chunk. Grid 521 -> exactly 3 chunks/block (perfect balance at N=100K).
__global__ __launch_bounds__(256) void k_main(
    const float* __restrict__ X, const short* __restrict__ w1frag,
    const float* __restrict__ b1, const float* __restrict__ wdeg,
    float* __restrict__ partials, int nNodes) {
  __shared__ __align__(16) short w1s[16384];  // 32KB W1 B-frags
  __shared__ __align__(16) short xs[8192];    // 16KB A-tile
  __shared__ float wdeg_s[64];
  __shared__ float sred[128];

  int tid = threadIdx.x;
  {
    const f32x4* src = reinterpret_cast<const f32x4*>(w1frag);
    f32x4* dst = reinterpret_cast<f32x4*>(w1s);
#pragma unroll
    for (int i = 0; i < 8; ++i) dst[tid + i * 256] = src[tid + i * 256];
  }
  if (tid < 128) sred[tid] = 0.f;

  int lane = tid & 63, wave = tid >> 6;
  int rA = lane & 15;   // A-row in 16-row group / C-col low bits
  int kh = lane >> 4;   // k-offset group (0..3) / C-row group

  float b1r[8];
#pragma unroll
  for (int ct = 0; ct < 8; ++ct) b1r[ct] = b1[ct * 16 + rA];

  float sl[8] = {0, 0, 0, 0, 0, 0, 0, 0};
  int nChunks = (nNodes + 63) >> 6;
  __syncthreads();

  for (int c = blockIdx.x; c < nChunks; c += gridDim.x) {
    int row0 = c << 6;
    // ---- stage X tile: 64 rows x 512B coalesced -> swizzled bf16 LDS ----
#pragma unroll
    for (int p = 0; p < 4; ++p) {
      int j = p * 256 + tid;  // 16B-unit id = row*16 + kc
      int rl = j >> 4, kc = j & 15;
      int grow = row0 + rl;
      if (grow > nNodes - 1) grow = nNodes - 1;
      const f32x4* gp =
          reinterpret_cast<const f32x4*>(X + (size_t)grow * 128 + kc * 8);
      f32x4 lo = gp[0], hi = gp[1];
      short8 v;
#pragma unroll
      for (int ee = 0; ee < 4; ++ee) {
        v[ee] = to_bf16s(lo[ee]);
        v[4 + ee] = to_bf16s(hi[ee]);
      }
      int u = rl * 16 + (kc ^ (rl & 7));
      *reinterpret_cast<short8*>(&xs[u * 8]) = v;
    }
    if (tid < 64) {  // stage this chunk's weights (coalesced)
      int row = row0 + tid;
      wdeg_s[tid] = (row < nNodes) ? wdeg[row] : 0.f;
    }
    __syncthreads();

    // ---- MFMA: wave w owns local rows [w*16, w*16+16) ----
    int rloc = wave * 16 + rA;
    f32x4 acc[8];
#pragma unroll
    for (int ct = 0; ct < 8; ++ct) acc[ct] = f32x4{0.f, 0.f, 0.f, 0.f};
#pragma unroll
    for (int ks = 0; ks < 4; ++ks) {
      int kc = ks * 4 + kh;
      int u = rloc * 16 + (kc ^ (rloc & 7));
      short8 a = *reinterpret_cast<const short8*>(&xs[u * 8]);
#pragma unroll
      for (int ct = 0; ct < 8; ++ct) {
        short8 bfr = *reinterpret_cast<const short8*>(
            &w1s[((ct * 4 + ks) * 64 + lane) * 8]);
        acc[ct] = __builtin_amdgcn_mfma_f32_16x16x32_bf16(a, bfr, acc[ct], 0, 0, 0);
      }
    }
    // ---- epilogue: C elem (ct,rr): local row = wave*16+kh*4+rr ----
#pragma unroll
    for (int rr = 0; rr < 4; ++rr) {
      int rl = wave * 16 + kh * 4 + rr;
      float w = wdeg_s[rl];
#pragma unroll
      for (int ct = 0; ct < 8; ++ct)
        sl[ct] += w * fmaxf(acc[ct][rr] + b1r[ct], 0.f);
    }
    __syncthreads();  // protect xs/wdeg_s before next chunk
  }

  // ---- fold lane groups -> sred -> partials[blockIdx] (plain store) ----
#pragma unroll
  for (int ct = 0; ct < 8; ++ct) {
    float v = sl[ct];
    v += __shfl_xor(v, 16);
    v += __shfl_xor(v, 32);
    if (kh == 0) atomicAdd(&sred[ct * 16 + rA], v);
  }
  __syncthreads();
  if (tid < 128) partials[(size_t)blockIdx.x * 128 + tid] = sred[tid];
}

// ---------------------------------------------------------------------------
// Reduce partials[B][128] -> sv; out = ((sv@W2 + (N+E)*b2)/N)@Wp + bp.
// Single block, 1024 threads; 32-way sliced f32x4 reduction, unrolled MLP.
__global__ __launch_bounds__(1024) void k_final(
    const float* __restrict__ partials, int B, const float* __restrict__ W2,
    const float* __restrict__ b2, const float* __restrict__ Wp,
    const float* __restrict__ bp, float* __restrict__ out,
    float totalW, float invN) {
  __shared__ float accsA[32 * 128];  // 16KB
  __shared__ float sv[128];
  __shared__ float pooled[128];
  int t = threadIdx.x;
  {  // phase A: 32 slices x 32 f32x4 col-groups over B rows
    int cg = t & 31, slc = t >> 5;
    f32x4 s = f32x4{0.f, 0.f, 0.f, 0.f};
#pragma unroll 4
    for (int r = slc; r < B; r += 32)
      s += *reinterpret_cast<const f32x4*>(partials + (size_t)r * 128 + cg * 4);
    *reinterpret_cast<f32x4*>(&accsA[slc * 128 + cg * 4]) = s;
  }
  __syncthreads();
  if (t < 128) {
    float v = 0.f;
#pragma unroll
    for (int i = 0; i < 32; ++i) v += accsA[i * 128 + t];
    sv[t] = v;
  }
  __syncthreads();
  {  // pooled = (sv@W2 + totalW*b2)*invN ; 8 k-slices x 128 cols
    int col = t & 127, sl8 = t >> 7;
    float a = 0.f;
#pragma unroll
    for (int kk = 0; kk < 16; ++kk) {
      int k = sl8 * 16 + kk;
      a += sv[k] * W2[k * 128 + col];
    }
    accsA[sl8 * 128 + col] = a;
  }
  __syncthreads();
  if (t < 128) {
    float v = totalW * b2[t];
#pragma unroll
    for (int i = 0; i < 8; ++i) v += accsA[i * 128 + t];
    pooled[t] = v * invN;
  }
  __syncthreads();
  if (t < 512) {  // out = pooled@Wp + bp ; 64 outs x 8 k-slices
    int o = t & 63, s2 = t >> 6;
    float a = 0.f;
#pragma unroll
    for (int kk = 0; kk < 16; ++kk) {
      int k = s2 * 16 + kk;
      a += pooled[k] * Wp[k * 64 + o];
    }
    accsA[s2 * 64 + o] = a;
  }
  __syncthreads();
  if (t < 64) {
    float v = bp[t];
#pragma unroll
    for (int i = 0; i < 8; ++i) v += accsA[i * 64 + t];
    out[t] = v;
  }
}

// ---------------------------------------------------------------------------
// Fallback path (ws too small / shapes out of range): zero + atomic hist + cvt.
__global__ void k_zero(unsigned* __restrict__ p, int n) {
  int i = blockIdx.x * 256 + threadIdx.x;
  if (i < n) p[i] = 0u;
}
__global__ __launch_bounds__(256) void k_hist_fb(const int* __restrict__ e,
                                                 unsigned* __restrict__ deg,
                                                 int E) {
  __shared__ int is64s;
  int tid = threadIdx.x;
  if (tid < 64) {
    unsigned long long bl = __ballot(e[2 * tid + 1] == 0);
    if (tid == 0) is64s = (__popcll(bl) > 32) ? 1 : 0;
  }
  __syncthreads();
  int is64 = is64s;
  int stride = gridDim.x * blockDim.x;
  for (int i = blockIdx.x * blockDim.x + tid; i < E; i += stride)
    atomicAdd(&deg[is64 ? (unsigned)e[2 * i] : (unsigned)e[i]], 1u);
}
__global__ void k_cvt(const unsigned* __restrict__ deg,
                      float* __restrict__ wdeg, int N) {
  int i = blockIdx.x * 256 + threadIdx.x;
  if (i < N) wdeg[i] = 1.0f + (float)deg[i];
}

// ---------------------------------------------------------------------------
extern "C" void kernel_launch(void* const* d_in, const int* in_sizes, int n_in,
                              void* d_out, int out_size, void* d_ws, size_t ws_size,
                              hipStream_t stream) {
  const float* X  = (const float*)d_in[0];
  const int*   ei = (const int*)d_in[1];
  const float* W1 = (const float*)d_in[2];
  const float* b1 = (const float*)d_in[3];
  const float* W2 = (const float*)d_in[4];
  const float* b2 = (const float*)d_in[5];
  const float* Wp = (const float*)d_in[6];
  const float* bp = (const float*)d_in[7];

  int N = in_sizes[0] / 128;
  int E = in_sizes[1] / 2;
  int nChunks = (N + 63) >> 6;  // 64-row chunks (1563 at N=100K)
  int mb = nChunks < 521 ? nChunks : 521;  // 3 chunks/block, perfectly balanced

  size_t privB = (size_t)NRANGE * NS * RW * 4;                // 6.55 MB
  size_t fragB = (16384 * 2 + 255) & ~(size_t)255;
  size_t wdegB = ((size_t)N * 4 + 255) & ~(size_t)255;
  size_t partB = ((size_t)mb * 128 * 4 + 255) & ~(size_t)255;
  size_t fixed = privB + fragB + wdegB + partB + 512;

  bool fast = (N <= NRANGE * RNODES) && (E / NS <= 65000) && (ws_size >= fixed);

  char* p = (char*)d_ws;
  unsigned* priv = (unsigned*)p;  p += privB;
  short* frag = (short*)p;        p += fragB;
  float* wdeg = (float*)p;        p += wdegB;
  float* parts = (float*)p;

  if (fast) {
    k_histprep<<<NFRAG + NRANGE * NS, 1024, 0, stream>>>(ei, priv, frag, W1, E);
    k_merge<<<(NRANGE * RW + 255) / 256, 256, 0, stream>>>(priv, wdeg, N);
  } else {
    k_histprep<<<NFRAG, 1024, 0, stream>>>(ei, priv, frag, W1, E);
    k_zero<<<(N + 255) / 256, 256, 0, stream>>>((unsigned*)wdeg, N);
    k_hist_fb<<<2048, 256, 0, stream>>>(ei, (unsigned*)wdeg, E);
    k_cvt<<<(N + 255) / 256, 256, 0, stream>>>((unsigned*)wdeg, wdeg, N);
  }
  k_main<<<mb, 256, 0, stream>>>(X, frag, b1, wdeg, parts, N);
  k_final<<<1, 1024, 0, stream>>>(parts, mb, W2, b2, Wp, bp, (float*)d_out,
                                  (float)N + (float)E, 1.0f / (float)N);
}